// Round 3
// baseline (358.247 us; speedup 1.0000x reference)
//
#include <hip/hip_runtime.h>

// Guided filter, fused single kernel. Round 5 (second resubmit — two prior
// GPUAcquisitionTimeouts, kernel has never been measured):
// - sIP LDS staging DELETED: stage-A threads read their 4-col raw window
//   directly from global (L1/L2-hot, working set 10.9KB/tile). Two 8B-aligned
//   float2 loads per array per row replace {stage1 global->LDS + LDS reads}.
// - One barrier per tile (was two). LDS = sAB only (9.5KB) -> 8 blocks/CU.
// - Rebalanced: stage A 33 pair-cols x 6 strips = 198 threads (was 99);
//   stage B 32 pair-cols x 8 strips = 256 threads (was 128).
// - Interior-block specialization kept (counts == 9, no bounds code).

constexpr int W  = 512;
constexpr int H  = 512;
constexpr int TW = 64;
constexpr int TH = 16;
constexpr int ABH = TH + 2;   // 18 rows of (a,b), halo 1
constexpr int ABW = TW + 2;   // 66 cols
constexpr float EPS  = 0.01f;
constexpr float INV9 = 1.0f / 9.0f;

template<bool INT>
__device__ __forceinline__ void run_tile(
    const float* __restrict__ Ibase, const float* __restrict__ Pbase,
    float* __restrict__ Obase, int x0, int y0, int tid,
    float2 (*sAB)[ABW])
{
    // ---- Stage A: a,b for 66x18 region, raw (I,P) direct from global. ----
    // 33 pair-cols x 6 strips of 3 ab-rows (5 raw rows each) = 198 threads.
    if (tid < 198) {
        const int s   = tid / 33;         // strip 0..5
        const int p   = tid - 33 * s;     // pair-col 0..32 -> ab cols 2p, 2p+1
        const int ay0 = 3 * s;            // ab rows ay0..ay0+2
        const int gx  = x0 - 2 + 2 * p;   // raw cols gx..gx+3 (even -> 8B aligned)
        const int gy0 = y0 - 2 + ay0;     // raw rows gy0..gy0+4

        float hI[2][3], hP[2][3], hII[2][3], hIP[2][3];
        #pragma unroll
        for (int j = 0; j < 5; ++j) {
            const int gy = gy0 + j;
            float i0, i1, i2, i3, q0, q1, q2, q3;
            if (INT) {
                const int g = gy * W + gx;
                const float2 a01 = *(const float2*)(Ibase + g);
                const float2 a23 = *(const float2*)(Ibase + g + 2);
                const float2 b01 = *(const float2*)(Pbase + g);
                const float2 b23 = *(const float2*)(Pbase + g + 2);
                i0 = a01.x; i1 = a01.y; i2 = a23.x; i3 = a23.y;
                q0 = b01.x; q1 = b01.y; q2 = b23.x; q3 = b23.y;
            } else {
                i0 = i1 = i2 = i3 = 0.f; q0 = q1 = q2 = q3 = 0.f;
                if ((unsigned)gy < (unsigned)H) {
                    const float* Ir = Ibase + gy * W;
                    const float* Pr = Pbase + gy * W;
                    if (gx >= 0 && gx + 3 < W) {
                        const float2 a01 = *(const float2*)(Ir + gx);
                        const float2 a23 = *(const float2*)(Ir + gx + 2);
                        const float2 b01 = *(const float2*)(Pr + gx);
                        const float2 b23 = *(const float2*)(Pr + gx + 2);
                        i0 = a01.x; i1 = a01.y; i2 = a23.x; i3 = a23.y;
                        q0 = b01.x; q1 = b01.y; q2 = b23.x; q3 = b23.y;
                    } else {
                        if ((unsigned)(gx + 0) < (unsigned)W) { i0 = Ir[gx + 0]; q0 = Pr[gx + 0]; }
                        if ((unsigned)(gx + 1) < (unsigned)W) { i1 = Ir[gx + 1]; q1 = Pr[gx + 1]; }
                        if ((unsigned)(gx + 2) < (unsigned)W) { i2 = Ir[gx + 2]; q2 = Pr[gx + 2]; }
                        if ((unsigned)(gx + 3) < (unsigned)W) { i3 = Ir[gx + 3]; q3 = Pr[gx + 3]; }
                    }
                }
            }
            const int k = j % 3;
            const float tI  = i1 + i2, tP = q1 + q2;
            const float tII = fmaf(i1, i1, i2 * i2);
            const float tIP = fmaf(i1, q1, i2 * q2);
            hI[0][k]  = tI + i0;            hI[1][k]  = tI + i3;
            hP[0][k]  = tP + q0;            hP[1][k]  = tP + q3;
            hII[0][k] = fmaf(i0, i0, tII);  hII[1][k] = fmaf(i3, i3, tII);
            hIP[0][k] = fmaf(i0, q0, tIP);  hIP[1][k] = fmaf(i3, q3, tIP);
            if (j >= 2) {
                const int ay = ay0 + j - 2;
                float ab[4];
                #pragma unroll
                for (int c = 0; c < 2; ++c) {
                    const float wI  = hI[c][0]  + hI[c][1]  + hI[c][2];
                    const float wP  = hP[c][0]  + hP[c][1]  + hP[c][2];
                    const float wII = hII[c][0] + hII[c][1] + hII[c][2];
                    const float wIP = hIP[c][0] + hIP[c][1] + hIP[c][2];
                    float a = 0.f, b = 0.f;
                    if (INT) {
                        const float mI   = wI * INV9, mP = wP * INV9;
                        const float varI = fmaf(-mI, mI, wII * INV9);
                        const float cov  = fmaf(-mI, mP, wIP * INV9);
                        a = cov * __builtin_amdgcn_rcpf(varI + EPS);
                        b = fmaf(-a, mI, mP);
                    } else {
                        const int axg = x0 - 1 + 2 * p + c;
                        const int ayg = y0 - 1 + ay;
                        if ((unsigned)axg < (unsigned)W && (unsigned)ayg < (unsigned)H) {
                            const float cx = 3.f - (float)(axg == 0) - (float)(axg == W - 1);
                            const float cy = 3.f - (float)(ayg == 0) - (float)(ayg == H - 1);
                            const float inv  = __builtin_amdgcn_rcpf(cx * cy);
                            const float mI   = wI * inv, mP = wP * inv;
                            const float varI = fmaf(-mI, mI, wII * inv);
                            const float cov  = fmaf(-mI, mP, wIP * inv);
                            a = cov * __builtin_amdgcn_rcpf(varI + EPS);
                            b = fmaf(-a, mI, mP);
                        }
                    }
                    ab[2 * c] = a; ab[2 * c + 1] = b;
                }
                *(float4*)&sAB[ay][2 * p] = make_float4(ab[0], ab[1], ab[2], ab[3]);
            }
        }
    }
    __syncthreads();

    // ---- Stage B: blur a,b; 32 out col-pairs x 8 strips of 2 rows = 256 thr ----
    {
        const int q   = tid & 31;
        const int r   = tid >> 5;         // 0..7
        const int ox0 = 2 * q;
        const int oy0 = 2 * r;            // ab rows oy0..oy0+3
        float hA[2][3], hB[2][3];
        #pragma unroll
        for (int j = 0; j < 4; ++j) {
            const float4 c01 = *(const float4*)&sAB[oy0 + j][ox0];
            const float4 c23 = *(const float4*)&sAB[oy0 + j][ox0 + 2];
            const float a0 = c01.x, b0 = c01.y, a1 = c01.z, b1 = c01.w;
            const float a2 = c23.x, b2 = c23.y, a3 = c23.z, b3 = c23.w;
            const int k = j % 3;
            const float tA = a1 + a2, tB = b1 + b2;
            hA[0][k] = tA + a0; hA[1][k] = tA + a3;
            hB[0][k] = tB + b0; hB[1][k] = tB + b3;
            if (j >= 2) {
                const int oy = oy0 + j - 2;
                const int gy = y0 + oy;
                const int go = gy * W + x0 + ox0;
                const float2 iv = *(const float2*)(Ibase + go);   // L1/L2 hit
                float res[2];
                #pragma unroll
                for (int c = 0; c < 2; ++c) {
                    const float sa = hA[c][0] + hA[c][1] + hA[c][2];
                    const float sb = hB[c][0] + hB[c][1] + hB[c][2];
                    float inv;
                    if (INT) {
                        inv = INV9;
                    } else {
                        const int gxo = x0 + ox0 + c;
                        const float cx = 3.f - (float)(gxo == 0) - (float)(gxo == W - 1);
                        const float cy = 3.f - (float)(gy == 0) - (float)(gy == H - 1);
                        inv = __builtin_amdgcn_rcpf(cx * cy);
                    }
                    const float Ic = (c == 0) ? iv.x : iv.y;
                    res[c] = fmaf(sa * inv, Ic, sb * inv);
                }
                *(float2*)(Obase + go) = make_float2(res[0], res[1]);
            }
        }
    }
}

__global__ __launch_bounds__(256, 8) void guide_filter_kernel(
    const float* __restrict__ I, const float* __restrict__ P,
    float* __restrict__ O)
{
    __shared__ __align__(16) float2 sAB[ABH][ABW];

    const int tid = threadIdx.x;
    const int x0  = blockIdx.x * TW;
    const int y0  = blockIdx.y * TH;
    const size_t img_off = (size_t)blockIdx.z * (size_t)(W * H);
    const bool interior = (blockIdx.x > 0) & (blockIdx.x < gridDim.x - 1) &
                          (blockIdx.y > 0) & (blockIdx.y < gridDim.y - 1);
    if (interior) {
        run_tile<true >(I + img_off, P + img_off, (float*)O + img_off, x0, y0, tid, sAB);
    } else {
        run_tile<false>(I + img_off, P + img_off, (float*)O + img_off, x0, y0, tid, sAB);
    }
}

extern "C" void kernel_launch(void* const* d_in, const int* in_sizes, int n_in,
                              void* d_out, int out_size, void* d_ws, size_t ws_size,
                              hipStream_t stream) {
    const float* I = (const float*)d_in[0];   // input
    const float* P = (const float*)d_in[1];   // guide
    float*       O = (float*)d_out;
    const int images = in_sizes[0] / (W * H); // B*C = 128
    dim3 grid(W / TW, H / TH, images);
    guide_filter_kernel<<<grid, dim3(256), 0, stream>>>(I, P, O);
}

// Round 8
// 331.973 us; speedup vs baseline: 1.0791x; 1.0791x over previous
//
#include <hip/hip_runtime.h>

// Guided filter, Round 8: barrier-free wave-autonomous scanline.
// r6 post-mortem: occupancy 90%, VALUBusy 57%, dur 121us -> phase/barrier
// convoy is structural. This version has ZERO barriers and ZERO LDS:
// - wave64 owns a 128-raw-col band (2 cols/lane, float2 loads) x 64 out rows.
// - horizontal 3-taps via __shfl lane+-1 (8 shuffles/row-iter).
// - vertical 3-taps via 3-slot register rings, manual x3 unroll so all ring
//   indices are compile-time (no scratch).
// - ab->out is a 2-row in-register pipeline within the scan (68 iters/wave).
// - boundaries fully branchless: zero-loads outside image, ab zeroed outside,
//   counts via rcp(cx*cy) everywhere (count_include_pad=False semantics).
// - bands: 5 x 120 out cols (lanes 1..60 store float2); row-groups: 8 x 64.
//   5120 independent waves, 4 waves/block, grid (5, 2, images).

constexpr int W = 512, H = 512;
constexpr int OUTW = 120;     // output cols per band (raw span 128)
constexpr int RG_H = 64;      // output rows per wave
constexpr float EPS = 0.01f;

#define GF_AB_COL(cx, wI, wP, wII, wIP, aa, bb)                               \
    {                                                                         \
        const float inv = __builtin_amdgcn_rcpf((cx) * cyA);                  \
        const float mI = (wI) * inv, mP = (wP) * inv;                         \
        const float varI = fmaf(-mI, mI, (wII) * inv);                        \
        const float cov  = fmaf(-mI, mP, (wIP) * inv);                        \
        aa = cov * __builtin_amdgcn_rcpf(varI + EPS);                         \
        bb = fmaf(-aa, mI, mP);                                               \
    }

#define GF_STEP(r, S, SP1)                                                    \
  {                                                                           \
    const int gy = oy0 - 2 + (r);                                             \
    const bool yok = (unsigned)gy < (unsigned)H;                              \
    float ix = 0.f, iy = 0.f, px = 0.f, py = 0.f;                             \
    if (xok & yok) {                                                          \
        const float2 vi = *(const float2*)(Ib + gy * W + c0);                 \
        const float2 vp = *(const float2*)(Pb + gy * W + c0);                 \
        ix = vi.x; iy = vi.y; px = vp.x; py = vp.y;                           \
    }                                                                         \
    const float iLy = __shfl(iy, lm1);                                        \
    const float pLy = __shfl(py, lm1);                                        \
    const float iRx = __shfl(ix, lp1);                                        \
    const float pRx = __shfl(px, lp1);                                        \
    const float cI = ix + iy, cP = px + py;                                   \
    hI0[S] = cI + iLy;  hI1[S] = cI + iRx;                                    \
    hP0[S] = cP + pLy;  hP1[S] = cP + pRx;                                    \
    const float cII = fmaf(ix, ix, iy * iy);                                  \
    const float cIP = fmaf(ix, px, iy * py);                                  \
    hII0[S] = fmaf(iLy, iLy, cII);  hII1[S] = fmaf(iRx, iRx, cII);            \
    hIP0[S] = fmaf(iLy, pLy, cIP);  hIP1[S] = fmaf(iRx, pRx, cIP);            \
    iC0[S] = ix; iC1[S] = iy;                                                 \
    const int ay = gy - 1;                                                    \
    const float cyA = 3.f - (float)(ay == 0) - (float)(ay == H - 1);          \
    const bool abok = xok & ((unsigned)ay < (unsigned)H);                     \
    float a0, b0, a1, b1;                                                     \
    GF_AB_COL(cx0, hI0[0] + hI0[1] + hI0[2], hP0[0] + hP0[1] + hP0[2],        \
              hII0[0] + hII0[1] + hII0[2], hIP0[0] + hIP0[1] + hIP0[2],       \
              a0, b0)                                                         \
    GF_AB_COL(cx1, hI1[0] + hI1[1] + hI1[2], hP1[0] + hP1[1] + hP1[2],        \
              hII1[0] + hII1[1] + hII1[2], hIP1[0] + hIP1[1] + hIP1[2],       \
              a1, b1)                                                         \
    a0 = abok ? a0 : 0.f;  b0 = abok ? b0 : 0.f;                              \
    a1 = abok ? a1 : 0.f;  b1 = abok ? b1 : 0.f;                              \
    const float aLy = __shfl(a1, lm1);                                        \
    const float bLy = __shfl(b1, lm1);                                        \
    const float aRx = __shfl(a0, lp1);                                        \
    const float bRx = __shfl(b0, lp1);                                        \
    const float cA = a0 + a1, cB = b0 + b1;                                   \
    hA0[S] = cA + aLy;  hA1[S] = cA + aRx;                                    \
    hB0[S] = cB + bLy;  hB1[S] = cB + bRx;                                    \
    if ((r) >= 4) {                                                           \
        const int oy = gy - 2;                                                \
        const float cyO = 3.f - (float)(oy == 0) - (float)(oy == H - 1);      \
        const float q0 = __builtin_amdgcn_rcpf(cx0 * cyO);                    \
        const float q1 = __builtin_amdgcn_rcpf(cx1 * cyO);                    \
        const float sA0 = hA0[0] + hA0[1] + hA0[2];                           \
        const float sB0 = hB0[0] + hB0[1] + hB0[2];                           \
        const float sA1 = hA1[0] + hA1[1] + hA1[2];                           \
        const float sB1 = hB1[0] + hB1[1] + hB1[2];                           \
        const float o0 = fmaf(sA0 * q0, iC0[SP1], sB0 * q0);                  \
        const float o1 = fmaf(sA1 * q1, iC1[SP1], sB1 * q1);                  \
        if (stok) *(float2*)(Ob + oy * W + c0) = make_float2(o0, o1);         \
    }                                                                         \
  }

__global__ __launch_bounds__(256, 4) void guide_filter_kernel(
    const float* __restrict__ I, const float* __restrict__ P,
    float* __restrict__ O)
{
    const int lane = threadIdx.x & 63;
    const int wid  = threadIdx.x >> 6;
    const int band = blockIdx.x;                  // 0..4
    const int rg   = blockIdx.y * 4 + wid;        // 0..7
    const size_t img_off = (size_t)blockIdx.z * (size_t)(W * H);
    const float* Ib = I + img_off;
    const float* Pb = P + img_off;
    float*       Ob = O + img_off;

    const int c0 = band * OUTW - 2 + 2 * lane;    // even -> float2 aligned
    const int c1 = c0 + 1;
    const bool xok  = (unsigned)c0 < (unsigned)W; // c0 valid => c1 valid (W even)
    const bool stok = xok & (lane >= 1) & (lane <= 60);
    const float cx0 = 3.f - (float)(c0 == 0);     // c0 is even, never W-1
    const float cx1 = 3.f - (float)(c1 == W - 1); // c1 is odd, never 0
    const int oy0 = rg * RG_H;
    const int lm1 = lane - 1, lp1 = lane + 1;

    float hI0[3], hI1[3], hP0[3], hP1[3], hII0[3], hII1[3], hIP0[3], hIP1[3];
    float hA0[3], hA1[3], hB0[3], hB1[3], iC0[3], iC1[3];
    #pragma unroll
    for (int s = 0; s < 3; ++s) {
        hI0[s]=hI1[s]=hP0[s]=hP1[s]=hII0[s]=hII1[s]=hIP0[s]=hIP1[s]=0.f;
        hA0[s]=hA1[s]=hB0[s]=hB1[s]=iC0[s]=iC1[s]=0.f;
    }

    // 68 raw-row iterations: 22 groups of 3 (static ring slots) + 2 tail.
    for (int g = 0; g < 22; ++g) {
        const int r = 3 * g;
        GF_STEP(r,     0, 1)
        GF_STEP(r + 1, 1, 2)
        GF_STEP(r + 2, 2, 0)
    }
    GF_STEP(66, 0, 1)
    GF_STEP(67, 1, 2)
}

extern "C" void kernel_launch(void* const* d_in, const int* in_sizes, int n_in,
                              void* d_out, int out_size, void* d_ws, size_t ws_size,
                              hipStream_t stream) {
    const float* I = (const float*)d_in[0];   // input
    const float* P = (const float*)d_in[1];   // guide
    float*       O = (float*)d_out;
    const int images = in_sizes[0] / (W * H); // B*C = 128
    dim3 grid(5, 2, images);                  // 5 bands x (2x4 waves) row-groups
    guide_filter_kernel<<<grid, dim3(256), 0, stream>>>(I, P, O);
}